// Round 5
// baseline (296.752 us; speedup 1.0000x reference)
//
#include <hip/hip_runtime.h>
#include <cstdint>

typedef __bf16 bf16x8 __attribute__((ext_vector_type(8)));
typedef float f32x16 __attribute__((ext_vector_type(16)));
typedef float f32x4 __attribute__((ext_vector_type(4)));

__device__ __forceinline__ unsigned short f2b(float f) {
    union { float f; uint32_t u; } x; x.f = f;
    uint32_t r = (x.u + 0x7fffu + ((x.u >> 16) & 1u)) >> 16;
    return (unsigned short)r;
}
__device__ __forceinline__ float b2f(unsigned short h) {
    union { float f; uint32_t u; } x; x.u = ((uint32_t)h) << 16;
    return x.f;
}

// ---------------- convert x (fp32 -> bf16), 4 elems/thread ----------------
__global__ __launch_bounds__(256) void convert_x_kernel(const float* __restrict__ x,
                                                        unsigned short* __restrict__ xb) {
    int i = (blockIdx.x * 256 + threadIdx.x) * 4;
    float4 v = *(const float4*)(x + i);
    ushort4 o;
    o.x = f2b(v.x); o.y = f2b(v.y); o.z = f2b(v.z); o.w = f2b(v.w);
    *(ushort4*)(xb + i) = o;
}

// ------------- transpose+convert W[k][n] -> Wt[n][k] (bf16) ---------------
__global__ __launch_bounds__(1024) void transpose_w_kernel(const float* __restrict__ Wq,
                                                           const float* __restrict__ Wk,
                                                           const float* __restrict__ Wv,
                                                           unsigned short* __restrict__ Wt) {
    __shared__ float tile[32][33];
    const float* W = (blockIdx.z == 0) ? Wq : (blockIdx.z == 1) ? Wk : Wv;
    int n0 = blockIdx.x * 32, k0 = blockIdx.y * 32;
    int tx = threadIdx.x, ty = threadIdx.y;
    tile[ty][tx] = W[(k0 + ty) * 1024 + n0 + tx];
    __syncthreads();
    Wt[((long)blockIdx.z * 1024 + n0 + ty) * 1024 + k0 + tx] = f2b(tile[tx][ty]);
}

// ============== 128x128 2-phase kernel (kept for PV: EPI 2) ==============
template <int EPI>
__global__ __launch_bounds__(256) void gemm32(const unsigned short* __restrict__ A, int lda, long sA,
                                              const unsigned short* __restrict__ Bm, int ldb, long sB,
                                              void* __restrict__ Cv, long sC, int K,
                                              const float* __restrict__ bq, const float* __restrict__ bk,
                                              const float* __restrict__ bv,
                                              unsigned short* __restrict__ Qb,
                                              unsigned short* __restrict__ Kb,
                                              unsigned short* __restrict__ Vt) {
    __shared__ unsigned short As0[128 * 64];
    __shared__ unsigned short Bs0[128 * 64];
    __shared__ unsigned short As1[128 * 64];
    __shared__ unsigned short Bs1[128 * 64];

    const int tid = threadIdx.x;
    const int wave = tid >> 6, lane = tid & 63;
    const int h = lane >> 5;
    const int l31 = lane & 31;
    const int wm = wave >> 1, wn = wave & 1;
    const long bm = (long)blockIdx.y * 128;
    const long bn = (long)blockIdx.x * 128;

    const unsigned short* Ab = A + (long)blockIdx.z * sA;
    const unsigned short* Bb = Bm + (long)blockIdx.z * sB;

    f32x16 acc[2][2];
#pragma unroll
    for (int mi = 0; mi < 2; ++mi) {
#pragma unroll
        for (int ni = 0; ni < 2; ++ni) {
#pragma unroll
            for (int r = 0; r < 16; ++r) acc[mi][ni][r] = 0.0f;
        }
    }

    const int srow_in = lane >> 3;
    const int cswz = (lane & 7) ^ srow_in;
    const unsigned short* aptr[4];
    const unsigned short* bptr[4];
    int sloff[4];
#pragma unroll
    for (int j = 0; j < 4; ++j) {
        const int row = j * 32 + wave * 8 + srow_in;
        aptr[j] = Ab + (bm + row) * (long)lda + cswz * 8;
        bptr[j] = Bb + (bn + row) * (long)ldb + cswz * 8;
        sloff[j] = (j * 32 + wave * 8) * 64;
    }

    const int arow0 = (wm * 64 + l31) * 64;
    const int brow0 = (wn * 64 + l31) * 64;
    int sw[4];
#pragma unroll
    for (int kh = 0; kh < 4; ++kh)
        sw[kh] = (((2 * kh + h) ^ (lane & 7)) * 8);

#define STAGE(AsB, BsB, kofs)                                                                           \
    do {                                                                                                \
        _Pragma("unroll")                                                                               \
        for (int j = 0; j < 4; ++j) {                                                                   \
            __builtin_amdgcn_global_load_lds(                                                           \
                (const __attribute__((address_space(1))) void*)(aptr[j] + (kofs)),                      \
                (__attribute__((address_space(3))) void*)(&AsB[sloff[j]]), 16, 0, 0);                   \
            __builtin_amdgcn_global_load_lds(                                                           \
                (const __attribute__((address_space(1))) void*)(bptr[j] + (kofs)),                      \
                (__attribute__((address_space(3))) void*)(&BsB[sloff[j]]), 16, 0, 0);                   \
        }                                                                                               \
    } while (0)

#define COMPUTE_T(AsB, BsB)                                                                             \
    do {                                                                                                \
        _Pragma("unroll")                                                                               \
        for (int kp = 0; kp < 2; ++kp) {                                                                \
            bf16x8 af[2][2], bfr[2][2];                                                                 \
            _Pragma("unroll")                                                                           \
            for (int mi = 0; mi < 2; ++mi) {                                                            \
                _Pragma("unroll")                                                                       \
                for (int kk = 0; kk < 2; ++kk) {                                                        \
                    af[mi][kk] = *(const bf16x8*)&AsB[arow0 + mi * 32 * 64 + sw[kp * 2 + kk]];          \
                }                                                                                       \
            }                                                                                           \
            _Pragma("unroll")                                                                           \
            for (int ni = 0; ni < 2; ++ni) {                                                            \
                _Pragma("unroll")                                                                       \
                for (int kk = 0; kk < 2; ++kk) {                                                        \
                    bfr[ni][kk] = *(const bf16x8*)&BsB[brow0 + ni * 32 * 64 + sw[kp * 2 + kk]];         \
                }                                                                                       \
            }                                                                                           \
            _Pragma("unroll")                                                                           \
            for (int kk = 0; kk < 2; ++kk) {                                                            \
                _Pragma("unroll")                                                                       \
                for (int mi = 0; mi < 2; ++mi) {                                                        \
                    _Pragma("unroll")                                                                   \
                    for (int ni = 0; ni < 2; ++ni) {                                                    \
                        acc[mi][ni] = __builtin_amdgcn_mfma_f32_32x32x16_bf16(af[mi][kk], bfr[ni][kk],  \
                                                                              acc[mi][ni], 0, 0, 0);    \
                    }                                                                                   \
                }                                                                                       \
            }                                                                                           \
        }                                                                                               \
    } while (0)

    STAGE(As0, Bs0, 0);

    for (int k0 = 0; k0 < K; k0 += 128) {
        __syncthreads();
        STAGE(As1, Bs1, k0 + 64);
        COMPUTE_T(As0, Bs0);
        __syncthreads();
        if (k0 + 128 < K) STAGE(As0, Bs0, k0 + 128);
        COMPUTE_T(As1, Bs1);
    }

#undef STAGE
#undef COMPUTE_T

#pragma unroll
    for (int mi = 0; mi < 2; ++mi) {
#pragma unroll
        for (int ni = 0; ni < 2; ++ni) {
            const f32x16 a = acc[mi][ni];
            const long col = bn + wn * 64 + ni * 32 + l31;
            const long rowB = bm + wm * 64 + mi * 32 + h * 4;
            if constexpr (EPI == 0) {
                if (col < 1024) {
                    const float bias = bq[col];
#pragma unroll
                    for (int g = 0; g < 4; ++g) {
#pragma unroll
                        for (int r = 0; r < 4; ++r)
                            Qb[(rowB + g * 8 + r) * 1024 + col] = f2b((a[g * 4 + r] + bias) * 0.03125f);
                    }
                } else if (col < 2048) {
                    const float bias = bk[col - 1024];
#pragma unroll
                    for (int g = 0; g < 4; ++g) {
#pragma unroll
                        for (int r = 0; r < 4; ++r)
                            Kb[(rowB + g * 8 + r) * 1024 + (col - 1024)] = f2b(a[g * 4 + r] + bias);
                    }
                } else {
                    const float bias = bv[col - 2048];
#pragma unroll
                    for (int g = 0; g < 4; ++g) {
                        const long row0 = rowB + g * 8;
                        const long batch = row0 >> 11;
                        const int n = (int)(row0 & 2047);
                        ushort4 o;
                        o.x = f2b(a[g * 4 + 0] + bias);
                        o.y = f2b(a[g * 4 + 1] + bias);
                        o.z = f2b(a[g * 4 + 2] + bias);
                        o.w = f2b(a[g * 4 + 3] + bias);
                        *(ushort4*)&Vt[(batch * 1024 + (col - 2048)) * 2048 + n] = o;
                    }
                }
            } else if constexpr (EPI == 1) {
                unsigned short* S = (unsigned short*)Cv + (long)blockIdx.z * sC;
#pragma unroll
                for (int g = 0; g < 4; ++g) {
#pragma unroll
                    for (int r = 0; r < 4; ++r)
                        S[(rowB + g * 8 + r) * 2048 + col] = f2b(a[g * 4 + r]);
                }
            } else {
                float* O = (float*)Cv + (long)blockIdx.z * sC;
#pragma unroll
                for (int g = 0; g < 4; ++g) {
#pragma unroll
                    for (int r = 0; r < 4; ++r)
                        O[(rowB + g * 8 + r) * 1024 + col] = a[g * 4 + r];
                }
            }
        }
    }
}

// ============== 256x256 8-phase counted-vmcnt kernel (QKV: EPI 0, scores: EPI 1) ==============
// Same schedule as the previous revision, but LDS is split into 8 STATICALLY NAMED arrays
// (one per half-tile region x double-buffer). Rationale: hipcc's waitcnt pass must protect
// ds_read against outstanding global_load_lds writes to the same LDS object; with a single
// As_/Bs_ array every phase's fragment reads trailed a just-issued load to that array and
// got an auto s_waitcnt vmcnt(0..2) -> full drain per phase (measured: MfmaUtil 20%,
// both pipes idle 68%). With named per-region arrays, each phase's reads are provably
// independent of all recently issued loads (nearest same-array load >= 10 vmcnt events
// older), so the auto-waits are no-ops and the hand-placed counted vmcnt(6/8) bind.
//
// Geometry: BM=BN=256, BK=64, 512 threads (8 waves, 2M x 4N), per-wave 128x64 out via
// mfma_f32_16x16x32_bf16 (acc[8][4] f32x4). LDS 8 x 16 KiB = 128 KiB.
// Region definitions (by consumption quadrant (qm,qn)):
//   Ah0 = A rows {0-63, 128-191} (qm=0 of both wave-halves): array row = wm*64 + r
//   Ah1 = A rows {64-127, 192-255} (qm=1)
//   Bh0 = B rows {0-31,64-95,128-159,192-223} (qn=0): array row = wn*32 + r
//   Bh1 = +32 (qn=1)
// Wait ledger (2 loads per half-tile per wave):
//   prologue issues 6 halves, vmcnt(4) => tile 0 resident
//   ph1/ph5 end: vmcnt(6) => current tile's h1 halves resident
//   ph4/ph8 end: vmcnt(8) => next tile's h0 halves resident; never vmcnt(0) in loop.
// LDS swizzle: 16B-chunk XOR by (row&7) applied via pre-swizzled global source; read-side
// XOR is lane-constant (fragment rows differ by multiples of 16).
template <int EPI>
__global__ __launch_bounds__(512, 2) void gemm256(const unsigned short* __restrict__ A, int lda, long sA,
                                                  const unsigned short* __restrict__ Bm, int ldb, long sB,
                                                  void* __restrict__ Cv, long sC, int K,
                                                  const float* __restrict__ bq, const float* __restrict__ bk,
                                                  const float* __restrict__ bv,
                                                  unsigned short* __restrict__ Qb,
                                                  unsigned short* __restrict__ Kb,
                                                  unsigned short* __restrict__ Vt) {
    __shared__ __align__(16) unsigned short Ah0_0[128 * 64];
    __shared__ __align__(16) unsigned short Ah1_0[128 * 64];
    __shared__ __align__(16) unsigned short Bh0_0[128 * 64];
    __shared__ __align__(16) unsigned short Bh1_0[128 * 64];
    __shared__ __align__(16) unsigned short Ah0_1[128 * 64];
    __shared__ __align__(16) unsigned short Ah1_1[128 * 64];
    __shared__ __align__(16) unsigned short Bh0_1[128 * 64];
    __shared__ __align__(16) unsigned short Bh1_1[128 * 64];

    const int tid = threadIdx.x;
    const int w = tid >> 6, l = tid & 63;
    const int wm = w >> 2, wn = w & 3;
    const long bm = (long)blockIdx.y * 256;
    const long bn = (long)blockIdx.x * 256;
    const unsigned short* Ab = A + (long)blockIdx.z * sA;
    const unsigned short* Bb = Bm + (long)blockIdx.z * sB;

    // staging lane constants: lane l covers row (+ l>>3), swizzled 16B chunk (l&7)^(l>>3)
    const int lrow = l >> 3;
    const int lchunk = (l & 7) ^ lrow;
    // fragment-read lane constants (16x16x32: row = l&15, k-group = l>>4)
    const int fr = l & 15, fg = l >> 4;
    const int kofs0 = ((fg) ^ (l & 7)) * 8;        // swizzled elem offset, k-sub 0
    const int kofs1 = ((4 + fg) ^ (l & 7)) * 8;    // k-sub 1
    const int abase = (wm * 64 + fr) * 64;         // within Ah{qm} array
    const int bbase = (wn * 32 + fr) * 64;         // within Bh{qn} array

    f32x4 acc[8][4];
#pragma unroll
    for (int mi = 0; mi < 8; ++mi) {
#pragma unroll
        for (int ni = 0; ni < 4; ++ni) {
#pragma unroll
            for (int r = 0; r < 4; ++r) acc[mi][ni][r] = 0.0f;
        }
    }

// stage half-tile region into its named array. DST row base j*64+w*8 (A) / (j*2+(w>>2))*32+(w&3)*8 (B).
#define ISSUE_A(DST, hh, T)                                                                              \
    {                                                                                                    \
        const int kk_ = ((T) * 64 < K) ? (T) * 64 : (K - 64);                                            \
        _Pragma("unroll")                                                                                \
        for (int j = 0; j < 2; ++j) {                                                                    \
            const int grow = (hh) * 64 + j * 128 + w * 8;                                                \
            const int arow = j * 64 + w * 8;                                                             \
            __builtin_amdgcn_global_load_lds(                                                            \
                (const __attribute__((address_space(1))) void*)(Ab + (bm + grow + lrow) * (long)lda + kk_ + lchunk * 8), \
                (__attribute__((address_space(3))) void*)(&DST[arow * 64]), 16, 0, 0);                   \
        }                                                                                                \
    }
#define ISSUE_B(DST, hh, T)                                                                              \
    {                                                                                                    \
        const int kk_ = ((T) * 64 < K) ? (T) * 64 : (K - 64);                                            \
        _Pragma("unroll")                                                                                \
        for (int j = 0; j < 2; ++j) {                                                                    \
            const int gb = (hh) * 32 + (w >> 2) * 64 + (w & 3) * 8 + j * 128;                            \
            const int brow_ = (j * 2 + (w >> 2)) * 32 + (w & 3) * 8;                                     \
            __builtin_amdgcn_global_load_lds(                                                            \
                (const __attribute__((address_space(1))) void*)(Bb + (bn + gb + lrow) * (long)ldb + kk_ + lchunk * 8), \
                (__attribute__((address_space(3))) void*)(&DST[brow_ * 64]), 16, 0, 0);                  \
        }                                                                                                \
    }
#define WAITV(n) asm volatile("s_waitcnt vmcnt(" #n ")" ::: "memory")

#define PHASE256(AARR, BARR, QM, QN, ISSUE_STMT, WAIT_STMT)                                              \
    {                                                                                                    \
        bf16x8 a_[4][2], b_[2][2];                                                                       \
        _Pragma("unroll")                                                                                \
        for (int mi = 0; mi < 4; ++mi) {                                                                 \
            a_[mi][0] = *(const bf16x8*)&AARR[abase + mi * 1024 + kofs0];                                \
            a_[mi][1] = *(const bf16x8*)&AARR[abase + mi * 1024 + kofs1];                                \
        }                                                                                                \
        _Pragma("unroll")                                                                                \
        for (int ni = 0; ni < 2; ++ni) {                                                                 \
            b_[ni][0] = *(const bf16x8*)&BARR[bbase + ni * 1024 + kofs0];                                \
            b_[ni][1] = *(const bf16x8*)&BARR[bbase + ni * 1024 + kofs1];                                \
        }                                                                                                \
        ISSUE_STMT;                                                                                      \
        __builtin_amdgcn_s_barrier();                                                                    \
        __builtin_amdgcn_sched_barrier(0);                                                               \
        __builtin_amdgcn_s_setprio(1);                                                                   \
        _Pragma("unroll")                                                                                \
        for (int ks = 0; ks < 2; ++ks) {                                                                 \
            _Pragma("unroll")                                                                            \
            for (int mi = 0; mi < 4; ++mi) {                                                             \
                _Pragma("unroll")                                                                        \
                for (int ni = 0; ni < 2; ++ni) {                                                         \
                    acc[(QM)*4 + mi][(QN)*2 + ni] = __builtin_amdgcn_mfma_f32_16x16x32_bf16(             \
                        a_[mi][ks], b_[ni][ks], acc[(QM)*4 + mi][(QN)*2 + ni], 0, 0, 0);                 \
                }                                                                                        \
            }                                                                                            \
        }                                                                                                \
        __builtin_amdgcn_s_setprio(0);                                                                   \
        WAIT_STMT;                                                                                       \
        __builtin_amdgcn_s_barrier();                                                                    \
        __builtin_amdgcn_sched_barrier(0);                                                               \
    }

    // ---- prologue: tile 0 complete + h0 halves of tile 1
    ISSUE_A(Ah0_0, 0, 0);
    ISSUE_B(Bh0_0, 0, 0);
    ISSUE_A(Ah1_0, 1, 0);
    ISSUE_B(Bh1_0, 1, 0);
    ISSUE_A(Ah0_1, 0, 1);
    ISSUE_B(Bh0_1, 0, 1);
    WAITV(4);
    __builtin_amdgcn_s_barrier();
    __builtin_amdgcn_sched_barrier(0);

    const int NT = K >> 6;
    for (int it = 0; it < NT; it += 2) {
        // tile it (buf0 arrays)
        PHASE256(Ah0_0, Bh0_0, 0, 0, ISSUE_A(Ah1_1, 1, it + 1), WAITV(6));
        PHASE256(Ah0_0, Bh1_0, 0, 1, ISSUE_B(Bh1_1, 1, it + 1), ((void)0));
        PHASE256(Ah1_0, Bh0_0, 1, 0, ISSUE_A(Ah0_0, 0, it + 2), ((void)0));
        PHASE256(Ah1_0, Bh1_0, 1, 1, ISSUE_B(Bh0_0, 0, it + 2), WAITV(8));
        // tile it+1 (buf1 arrays)
        PHASE256(Ah0_1, Bh0_1, 0, 0, ISSUE_A(Ah1_0, 1, it + 2), WAITV(6));
        PHASE256(Ah0_1, Bh1_1, 0, 1, ISSUE_B(Bh1_0, 1, it + 2), ((void)0));
        PHASE256(Ah1_1, Bh0_1, 1, 0, ISSUE_A(Ah0_1, 0, it + 3), ((void)0));
        PHASE256(Ah1_1, Bh1_1, 1, 1, ISSUE_B(Bh0_1, 0, it + 3), WAITV(8));
    }

    // drain outstanding DMA before epilogue
    asm volatile("s_waitcnt vmcnt(0)" ::: "memory");

#undef ISSUE_A
#undef ISSUE_B
#undef WAITV
#undef PHASE256

    // ---- epilogue. 16x16 C/D layout: col = l&15, row = (l>>4)*4 + reg
#pragma unroll
    for (int mi = 0; mi < 8; ++mi) {
        const long grow = bm + wm * 128 + mi * 16 + fg * 4;
#pragma unroll
        for (int ni = 0; ni < 4; ++ni) {
            const long gcol = bn + wn * 64 + ni * 16 + fr;
            const f32x4 a = acc[mi][ni];
            if constexpr (EPI == 0) {
                if (gcol < 1024) {
                    const float bias = bq[gcol];
#pragma unroll
                    for (int r = 0; r < 4; ++r)
                        Qb[(grow + r) * 1024 + gcol] = f2b((a[r] + bias) * 0.03125f);
                } else if (gcol < 2048) {
                    const float bias = bk[gcol - 1024];
#pragma unroll
                    for (int r = 0; r < 4; ++r)
                        Kb[(grow + r) * 1024 + (gcol - 1024)] = f2b(a[r] + bias);
                } else {
                    const float bias = bv[gcol - 2048];
                    const long batch = grow >> 11;
                    const int n = (int)(grow & 2047);   // multiple of 4
                    ushort4 o;
                    o.x = f2b(a[0] + bias);
                    o.y = f2b(a[1] + bias);
                    o.z = f2b(a[2] + bias);
                    o.w = f2b(a[3] + bias);
                    *(ushort4*)&Vt[(batch * 1024 + (gcol - 2048)) * 2048 + n] = o;
                }
            } else {
                unsigned short* S = (unsigned short*)Cv + (long)blockIdx.z * sC;
#pragma unroll
                for (int r = 0; r < 4; ++r)
                    S[(grow + r) * 2048 + gcol] = f2b(a[r]);
            }
        }
    }
}

// ---------------- row softmax over 2048 bf16, in place ----------------
__global__ __launch_bounds__(256) void softmax_kernel(unsigned short* __restrict__ S) {
    const long row = blockIdx.x;
    unsigned short* p = S + row * 2048;
    const int tid = threadIdx.x;
    const int wave = tid >> 6, lane = tid & 63;

    ushort4 u0 = *(const ushort4*)&p[tid * 8];
    ushort4 u1 = *(const ushort4*)&p[tid * 8 + 4];
    float v[8];
    v[0] = b2f(u0.x); v[1] = b2f(u0.y); v[2] = b2f(u0.z); v[3] = b2f(u0.w);
    v[4] = b2f(u1.x); v[5] = b2f(u1.y); v[6] = b2f(u1.z); v[7] = b2f(u1.w);

    float m = v[0];
#pragma unroll
    for (int j = 1; j < 8; ++j) m = fmaxf(m, v[j]);
#pragma unroll
    for (int off = 32; off; off >>= 1) m = fmaxf(m, __shfl_xor(m, off, 64));
    __shared__ float redm[4];
    __shared__ float reds[4];
    if (lane == 0) redm[wave] = m;
    __syncthreads();
    m = fmaxf(fmaxf(redm[0], redm[1]), fmaxf(redm[2], redm[3]));

    float s = 0.0f;
#pragma unroll
    for (int j = 0; j < 8; ++j) { v[j] = __expf(v[j] - m); s += v[j]; }
#pragma unroll
    for (int off = 32; off; off >>= 1) s += __shfl_xor(s, off, 64);
    if (lane == 0) reds[wave] = s;
    __syncthreads();
    s = reds[0] + reds[1] + reds[2] + reds[3];
    const float inv = 1.0f / s;

    u0.x = f2b(v[0] * inv); u0.y = f2b(v[1] * inv); u0.z = f2b(v[2] * inv); u0.w = f2b(v[3] * inv);
    u1.x = f2b(v[4] * inv); u1.y = f2b(v[5] * inv); u1.z = f2b(v[6] * inv); u1.w = f2b(v[7] * inv);
    *(ushort4*)&p[tid * 8] = u0;
    *(ushort4*)&p[tid * 8 + 4] = u1;
}

extern "C" void kernel_launch(void* const* d_in, const int* in_sizes, int n_in,
                              void* d_out, int out_size, void* d_ws, size_t ws_size,
                              hipStream_t stream) {
    const float* x  = (const float*)d_in[0];
    const float* Wq = (const float*)d_in[1];
    const float* Wk = (const float*)d_in[2];
    const float* Wv = (const float*)d_in[3];
    const float* bq = (const float*)d_in[4];
    const float* bk = (const float*)d_in[5];
    const float* bv = (const float*)d_in[6];
    float* out = (float*)d_out;

    char* ws = (char*)d_ws;
    unsigned short* xb = (unsigned short*)ws; ws += 8192L * 1024 * 2;
    unsigned short* Wt = (unsigned short*)ws; ws += 3072L * 1024 * 2;
    unsigned short* Qb = (unsigned short*)ws; ws += 8192L * 1024 * 2;
    unsigned short* Kb = (unsigned short*)ws; ws += 8192L * 1024 * 2;
    unsigned short* Vt = (unsigned short*)ws; ws += 4L * 1024 * 2048 * 2;
    unsigned short* S  = (unsigned short*)ws; ws += 4L * 2048 * 2048 * 2;

    // 1. x -> bf16
    convert_x_kernel<<<8192, 256, 0, stream>>>(x, xb);
    // 2. W -> Wt (bf16, transposed, packed [3072][1024])
    transpose_w_kernel<<<dim3(32, 32, 3), dim3(32, 32), 0, stream>>>(Wq, Wk, Wv, Wt);
    // 3. QKV projection: [8192,3072] = xb @ Wt^T (+bias, Q scaled, V stored transposed)
    gemm256<0><<<dim3(12, 32, 1), 512, 0, stream>>>(xb, 1024, 0, Wt, 1024, 0,
                                                    nullptr, 0, 1024, bq, bk, bv, Qb, Kb, Vt);
    // 4. per-batch scores: S[b] = Q[b] @ K[b]^T  (Q pre-scaled by 1/32)
    gemm256<1><<<dim3(8, 8, 4), 512, 0, stream>>>(Qb, 1024, 2048L * 1024, Kb, 1024, 2048L * 1024,
                                                  S, 2048L * 2048, 1024,
                                                  nullptr, nullptr, nullptr, nullptr, nullptr, nullptr);
    // 5. softmax rows (in place, bf16)
    softmax_kernel<<<8192, 256, 0, stream>>>(S);
    // 6. out[b] = P[b] @ Vt[b]^T  (fp32 out)
    gemm32<2><<<dim3(8, 16, 4), 256, 0, stream>>>(S, 2048, 2048L * 2048, Vt, 2048, 2048L * 1024,
                                                  out, 2048L * 1024, 2048,
                                                  nullptr, nullptr, nullptr, nullptr, nullptr, nullptr);
}

// Round 6
// 275.523 us; speedup vs baseline: 1.0770x; 1.0770x over previous
//
#include <hip/hip_runtime.h>
#include <cstdint>

typedef __bf16 bf16x8 __attribute__((ext_vector_type(8)));
typedef float f32x16 __attribute__((ext_vector_type(16)));
typedef float f32x4 __attribute__((ext_vector_type(4)));

__device__ __forceinline__ unsigned short f2b(float f) {
    union { float f; uint32_t u; } x; x.f = f;
    uint32_t r = (x.u + 0x7fffu + ((x.u >> 16) & 1u)) >> 16;
    return (unsigned short)r;
}
__device__ __forceinline__ float b2f(unsigned short h) {
    union { float f; uint32_t u; } x; x.u = ((uint32_t)h) << 16;
    return x.f;
}

// ---------------- convert x (fp32 -> bf16), 4 elems/thread ----------------
__global__ __launch_bounds__(256) void convert_x_kernel(const float* __restrict__ x,
                                                        unsigned short* __restrict__ xb) {
    int i = (blockIdx.x * 256 + threadIdx.x) * 4;
    float4 v = *(const float4*)(x + i);
    ushort4 o;
    o.x = f2b(v.x); o.y = f2b(v.y); o.z = f2b(v.z); o.w = f2b(v.w);
    *(ushort4*)(xb + i) = o;
}

// ------------- transpose+convert W[k][n] -> Wt[n][k] (bf16) ---------------
__global__ __launch_bounds__(1024) void transpose_w_kernel(const float* __restrict__ Wq,
                                                           const float* __restrict__ Wk,
                                                           const float* __restrict__ Wv,
                                                           unsigned short* __restrict__ Wt) {
    __shared__ float tile[32][33];
    const float* W = (blockIdx.z == 0) ? Wq : (blockIdx.z == 1) ? Wk : Wv;
    int n0 = blockIdx.x * 32, k0 = blockIdx.y * 32;
    int tx = threadIdx.x, ty = threadIdx.y;
    tile[ty][tx] = W[(k0 + ty) * 1024 + n0 + tx];
    __syncthreads();
    Wt[((long)blockIdx.z * 1024 + n0 + ty) * 1024 + k0 + tx] = f2b(tile[tx][ty]);
}

// ============== 128x128 2-phase kernel (kept for PV: EPI 2) ==============
template <int EPI>
__global__ __launch_bounds__(256) void gemm32(const unsigned short* __restrict__ A, int lda, long sA,
                                              const unsigned short* __restrict__ Bm, int ldb, long sB,
                                              void* __restrict__ Cv, long sC, int K,
                                              const float* __restrict__ bq, const float* __restrict__ bk,
                                              const float* __restrict__ bv,
                                              unsigned short* __restrict__ Qb,
                                              unsigned short* __restrict__ Kb,
                                              unsigned short* __restrict__ Vt) {
    __shared__ unsigned short As0[128 * 64];
    __shared__ unsigned short Bs0[128 * 64];
    __shared__ unsigned short As1[128 * 64];
    __shared__ unsigned short Bs1[128 * 64];

    const int tid = threadIdx.x;
    const int wave = tid >> 6, lane = tid & 63;
    const int h = lane >> 5;
    const int l31 = lane & 31;
    const int wm = wave >> 1, wn = wave & 1;
    const long bm = (long)blockIdx.y * 128;
    const long bn = (long)blockIdx.x * 128;

    const unsigned short* Ab = A + (long)blockIdx.z * sA;
    const unsigned short* Bb = Bm + (long)blockIdx.z * sB;

    f32x16 acc[2][2];
#pragma unroll
    for (int mi = 0; mi < 2; ++mi) {
#pragma unroll
        for (int ni = 0; ni < 2; ++ni) {
#pragma unroll
            for (int r = 0; r < 16; ++r) acc[mi][ni][r] = 0.0f;
        }
    }

    const int srow_in = lane >> 3;
    const int cswz = (lane & 7) ^ srow_in;
    const unsigned short* aptr[4];
    const unsigned short* bptr[4];
    int sloff[4];
#pragma unroll
    for (int j = 0; j < 4; ++j) {
        const int row = j * 32 + wave * 8 + srow_in;
        aptr[j] = Ab + (bm + row) * (long)lda + cswz * 8;
        bptr[j] = Bb + (bn + row) * (long)ldb + cswz * 8;
        sloff[j] = (j * 32 + wave * 8) * 64;
    }

    const int arow0 = (wm * 64 + l31) * 64;
    const int brow0 = (wn * 64 + l31) * 64;
    int sw[4];
#pragma unroll
    for (int kh = 0; kh < 4; ++kh)
        sw[kh] = (((2 * kh + h) ^ (lane & 7)) * 8);

#define STAGE(AsB, BsB, kofs)                                                                           \
    do {                                                                                                \
        _Pragma("unroll")                                                                               \
        for (int j = 0; j < 4; ++j) {                                                                   \
            __builtin_amdgcn_global_load_lds(                                                           \
                (const __attribute__((address_space(1))) void*)(aptr[j] + (kofs)),                      \
                (__attribute__((address_space(3))) void*)(&AsB[sloff[j]]), 16, 0, 0);                   \
            __builtin_amdgcn_global_load_lds(                                                           \
                (const __attribute__((address_space(1))) void*)(bptr[j] + (kofs)),                      \
                (__attribute__((address_space(3))) void*)(&BsB[sloff[j]]), 16, 0, 0);                   \
        }                                                                                               \
    } while (0)

#define COMPUTE_T(AsB, BsB)                                                                             \
    do {                                                                                                \
        _Pragma("unroll")                                                                               \
        for (int kp = 0; kp < 2; ++kp) {                                                                \
            bf16x8 af[2][2], bfr[2][2];                                                                 \
            _Pragma("unroll")                                                                           \
            for (int mi = 0; mi < 2; ++mi) {                                                            \
                _Pragma("unroll")                                                                       \
                for (int kk = 0; kk < 2; ++kk) {                                                        \
                    af[mi][kk] = *(const bf16x8*)&AsB[arow0 + mi * 32 * 64 + sw[kp * 2 + kk]];          \
                }                                                                                       \
            }                                                                                           \
            _Pragma("unroll")                                                                           \
            for (int ni = 0; ni < 2; ++ni) {                                                            \
                _Pragma("unroll")                                                                       \
                for (int kk = 0; kk < 2; ++kk) {                                                        \
                    bfr[ni][kk] = *(const bf16x8*)&BsB[brow0 + ni * 32 * 64 + sw[kp * 2 + kk]];         \
                }                                                                                       \
            }                                                                                           \
            _Pragma("unroll")                                                                           \
            for (int kk = 0; kk < 2; ++kk) {                                                            \
                _Pragma("unroll")                                                                       \
                for (int mi = 0; mi < 2; ++mi) {                                                        \
                    _Pragma("unroll")                                                                   \
                    for (int ni = 0; ni < 2; ++ni) {                                                    \
                        acc[mi][ni] = __builtin_amdgcn_mfma_f32_32x32x16_bf16(af[mi][kk], bfr[ni][kk],  \
                                                                              acc[mi][ni], 0, 0, 0);    \
                    }                                                                                   \
                }                                                                                       \
            }                                                                                           \
        }                                                                                               \
    } while (0)

    STAGE(As0, Bs0, 0);

    for (int k0 = 0; k0 < K; k0 += 128) {
        __syncthreads();
        STAGE(As1, Bs1, k0 + 64);
        COMPUTE_T(As0, Bs0);
        __syncthreads();
        if (k0 + 128 < K) STAGE(As0, Bs0, k0 + 128);
        COMPUTE_T(As1, Bs1);
    }

#undef STAGE
#undef COMPUTE_T

#pragma unroll
    for (int mi = 0; mi < 2; ++mi) {
#pragma unroll
        for (int ni = 0; ni < 2; ++ni) {
            const f32x16 a = acc[mi][ni];
            const long col = bn + wn * 64 + ni * 32 + l31;
            const long rowB = bm + wm * 64 + mi * 32 + h * 4;
            if constexpr (EPI == 0) {
                if (col < 1024) {
                    const float bias = bq[col];
#pragma unroll
                    for (int g = 0; g < 4; ++g) {
#pragma unroll
                        for (int r = 0; r < 4; ++r)
                            Qb[(rowB + g * 8 + r) * 1024 + col] = f2b((a[g * 4 + r] + bias) * 0.03125f);
                    }
                } else if (col < 2048) {
                    const float bias = bk[col - 1024];
#pragma unroll
                    for (int g = 0; g < 4; ++g) {
#pragma unroll
                        for (int r = 0; r < 4; ++r)
                            Kb[(rowB + g * 8 + r) * 1024 + (col - 1024)] = f2b(a[g * 4 + r] + bias);
                    }
                } else {
                    const float bias = bv[col - 2048];
#pragma unroll
                    for (int g = 0; g < 4; ++g) {
                        const long row0 = rowB + g * 8;
                        const long batch = row0 >> 11;
                        const int n = (int)(row0 & 2047);
                        ushort4 o;
                        o.x = f2b(a[g * 4 + 0] + bias);
                        o.y = f2b(a[g * 4 + 1] + bias);
                        o.z = f2b(a[g * 4 + 2] + bias);
                        o.w = f2b(a[g * 4 + 3] + bias);
                        *(ushort4*)&Vt[(batch * 1024 + (col - 2048)) * 2048 + n] = o;
                    }
                }
            } else if constexpr (EPI == 1) {
                unsigned short* S = (unsigned short*)Cv + (long)blockIdx.z * sC;
#pragma unroll
                for (int g = 0; g < 4; ++g) {
#pragma unroll
                    for (int r = 0; r < 4; ++r)
                        S[(rowB + g * 8 + r) * 2048 + col] = f2b(a[g * 4 + r]);
                }
            } else {
                float* O = (float*)Cv + (long)blockIdx.z * sC;
#pragma unroll
                for (int g = 0; g < 4; ++g) {
#pragma unroll
                    for (int r = 0; r < 4; ++r)
                        O[(rowB + g * 8 + r) * 1024 + col] = a[g * 4 + r];
                }
            }
        }
    }
}

// ============== 256x256 8-phase kernel with FRAGMENT REUSE (QKV: EPI 0, scores: EPI 1) ==============
// Diagnosis from rounds 4/5 (MfmaUtil 20%, both pipes idle 68%): per-phase re-reading of BOTH
// A and B fragments (12 ds_read_b128/wave/phase = 384 KB/tile block-wide) exceeded the LDS pipe
// floor (~3000-4500 cy/tile vs 2480 cy MFMA floor) and sat on the critical path. Fix:
// Gray-code quadrant order (0,0)->(0,1)->(1,1)->(1,0) with register reuse -> per-phase reads
// {12,4,8,0} = 24/tile (A0 reused ph1-2, B1 ph2-3, A1 ph3-4, B0 ph1&4). Reads are issued
// BEFORE each phase's first barrier so the barrier-wait hides their latency (template mechanism).
//
// DMA ledger (2 loads per ISSUE, per wave): prologue issues t0+t1 (16 loads), WAITV(8) -> t0
// resident. Per tile u: w2 issues Ah0,Bh0 of t(u+2) (+4), w3 Bh1 (+2), w4 Ah1 (+2) ->
// outstanding 16 at w4's WAITV(8), retiring t(u+1) for its w1. Never vmcnt(0) in the loop.
// Tail ISSUEs clamp k to K-64 (write-only dummies, same WAR windows). WAR safety: each
// region's ISSUE is >= 2 barriers after its last ds_read (A0/B0 read w1 -> issue w2;
// B1 read w2 -> issue w3; A1 read w3 -> issue w4).
template <int EPI>
__global__ __launch_bounds__(512, 2) void gemm256(const unsigned short* __restrict__ A, int lda, long sA,
                                                  const unsigned short* __restrict__ Bm, int ldb, long sB,
                                                  void* __restrict__ Cv, long sC, int K,
                                                  const float* __restrict__ bq, const float* __restrict__ bk,
                                                  const float* __restrict__ bv,
                                                  unsigned short* __restrict__ Qb,
                                                  unsigned short* __restrict__ Kb,
                                                  unsigned short* __restrict__ Vt) {
    __shared__ __align__(16) unsigned short Ah0_0[128 * 64];
    __shared__ __align__(16) unsigned short Ah1_0[128 * 64];
    __shared__ __align__(16) unsigned short Bh0_0[128 * 64];
    __shared__ __align__(16) unsigned short Bh1_0[128 * 64];
    __shared__ __align__(16) unsigned short Ah0_1[128 * 64];
    __shared__ __align__(16) unsigned short Ah1_1[128 * 64];
    __shared__ __align__(16) unsigned short Bh0_1[128 * 64];
    __shared__ __align__(16) unsigned short Bh1_1[128 * 64];

    const int tid = threadIdx.x;
    const int w = tid >> 6, l = tid & 63;
    const int wm = w >> 2, wn = w & 3;
    const long bm = (long)blockIdx.y * 256;
    const long bn = (long)blockIdx.x * 256;
    const unsigned short* Ab = A + (long)blockIdx.z * sA;
    const unsigned short* Bb = Bm + (long)blockIdx.z * sB;

    // staging lane constants: lane l covers row (+ l>>3), swizzled 16B chunk (l&7)^(l>>3)
    const int lrow = l >> 3;
    const int lchunk = (l & 7) ^ lrow;
    // fragment-read lane constants (16x16x32: row = l&15, k-group = l>>4)
    const int fr = l & 15, fg = l >> 4;
    const int kofs0 = ((fg) ^ (l & 7)) * 8;        // swizzled elem offset, k-sub 0
    const int kofs1 = ((4 + fg) ^ (l & 7)) * 8;    // k-sub 1
    const int abase = (wm * 64 + fr) * 64;         // within Ah{qm} array
    const int bbase = (wn * 32 + fr) * 64;         // within Bh{qn} array

    f32x4 acc[8][4];
#pragma unroll
    for (int mi = 0; mi < 8; ++mi) {
#pragma unroll
        for (int ni = 0; ni < 4; ++ni) {
#pragma unroll
            for (int r = 0; r < 4; ++r) acc[mi][ni][r] = 0.0f;
        }
    }

    bf16x8 af[4][2];    // current A fragment set (A0 in w1-w2, A1 in w3-w4)
    bf16x8 b0_[2][2];   // B quadrant 0 (live w1..w4)
    bf16x8 b1_[2][2];   // B quadrant 1 (live w2..w3)

#define ISSUE_A(DST, hh, T)                                                                              \
    {                                                                                                    \
        const int kk_ = ((T) * 64 < K) ? (T) * 64 : (K - 64);                                            \
        _Pragma("unroll")                                                                                \
        for (int j = 0; j < 2; ++j) {                                                                    \
            const int grow = (hh) * 64 + j * 128 + w * 8;                                                \
            const int arow = j * 64 + w * 8;                                                             \
            __builtin_amdgcn_global_load_lds(                                                            \
                (const __attribute__((address_space(1))) void*)(Ab + (bm + grow + lrow) * (long)lda + kk_ + lchunk * 8), \
                (__attribute__((address_space(3))) void*)(&DST[arow * 64]), 16, 0, 0);                   \
        }                                                                                                \
    }
#define ISSUE_B(DST, hh, T)                                                                              \
    {                                                                                                    \
        const int kk_ = ((T) * 64 < K) ? (T) * 64 : (K - 64);                                            \
        _Pragma("unroll")                                                                                \
        for (int j = 0; j < 2; ++j) {                                                                    \
            const int gb = (hh) * 32 + (w >> 2) * 64 + (w & 3) * 8 + j * 128;                            \
            const int brow_ = (j * 2 + (w >> 2)) * 32 + (w & 3) * 8;                                     \
            __builtin_amdgcn_global_load_lds(                                                            \
                (const __attribute__((address_space(1))) void*)(Bb + (bn + gb + lrow) * (long)ldb + kk_ + lchunk * 8), \
                (__attribute__((address_space(3))) void*)(&DST[brow_ * 64]), 16, 0, 0);                  \
        }                                                                                                \
    }
#define WAITV(n) asm volatile("s_waitcnt vmcnt(" #n ")" ::: "memory")

#define READ_A(SRC)                                                                                      \
    _Pragma("unroll")                                                                                    \
    for (int mi = 0; mi < 4; ++mi) {                                                                     \
        af[mi][0] = *(const bf16x8*)&SRC[abase + mi * 1024 + kofs0];                                     \
        af[mi][1] = *(const bf16x8*)&SRC[abase + mi * 1024 + kofs1];                                     \
    }
#define READ_B(DSTV, SRC)                                                                                \
    _Pragma("unroll")                                                                                    \
    for (int ni = 0; ni < 2; ++ni) {                                                                     \
        DSTV[ni][0] = *(const bf16x8*)&SRC[bbase + ni * 1024 + kofs0];                                   \
        DSTV[ni][1] = *(const bf16x8*)&SRC[bbase + ni * 1024 + kofs1];                                   \
    }
#define MFMA8(QM, QN, BF)                                                                                \
    __builtin_amdgcn_s_setprio(1);                                                                       \
    _Pragma("unroll")                                                                                    \
    for (int ks = 0; ks < 2; ++ks) {                                                                     \
        _Pragma("unroll")                                                                                \
        for (int mi = 0; mi < 4; ++mi) {                                                                 \
            _Pragma("unroll")                                                                            \
            for (int ni = 0; ni < 2; ++ni) {                                                             \
                acc[(QM)*4 + mi][(QN)*2 + ni] = __builtin_amdgcn_mfma_f32_16x16x32_bf16(                 \
                    af[mi][ks], BF[ni][ks], acc[(QM)*4 + mi][(QN)*2 + ni], 0, 0, 0);                     \
            }                                                                                            \
        }                                                                                                \
    }                                                                                                    \
    __builtin_amdgcn_s_setprio(0);

#define BAR() __builtin_amdgcn_s_barrier()
#define SCHED0() __builtin_amdgcn_sched_barrier(0)

// One K-tile (4 phases, Gray order). AH0.. are this tile's buffer arrays; U is the tile index.
#define TILE256(AH0, AH1, BH0, BH1, U)                                                                   \
    {                                                                                                    \
        /* w1: reads for (0,0); latency hidden under bar1 */                                             \
        READ_A(AH0);                                                                                     \
        READ_B(b0_, BH0);                                                                                \
        BAR();                                                                                           \
        MFMA8(0, 0, b0_);                                                                                \
        BAR(); SCHED0();                                                                                 \
        /* w2: read B1; prefetch t(U+2) Ah0,Bh0 (regions last read in w1) */                             \
        READ_B(b1_, BH1);                                                                                \
        ISSUE_A(AH0, 0, (U) + 2);                                                                        \
        ISSUE_B(BH0, 0, (U) + 2);                                                                        \
        BAR();                                                                                           \
        MFMA8(0, 1, b1_);                                                                                \
        BAR(); SCHED0();                                                                                 \
        /* w3: read A1; prefetch Bh1 (last read in w2) */                                                \
        READ_A(AH1);                                                                                     \
        ISSUE_B(BH1, 1, (U) + 2);                                                                        \
        BAR();                                                                                           \
        MFMA8(1, 1, b1_);                                                                                \
        BAR(); SCHED0();                                                                                 \
        /* w4: no reads (A1,B0 in regs); prefetch Ah1 (last read in w3); retire t(U+1) */                \
        ISSUE_A(AH1, 1, (U) + 2);                                                                        \
        BAR();                                                                                           \
        MFMA8(1, 0, b0_);                                                                                \
        WAITV(8);                                                                                        \
        BAR(); SCHED0();                                                                                 \
    }

    // ---- prologue: stage tiles 0 and 1 whole; wait tile 0 resident
    ISSUE_A(Ah0_0, 0, 0);
    ISSUE_B(Bh0_0, 0, 0);
    ISSUE_A(Ah1_0, 1, 0);
    ISSUE_B(Bh1_0, 1, 0);
    ISSUE_A(Ah0_1, 0, 1);
    ISSUE_B(Bh0_1, 0, 1);
    ISSUE_A(Ah1_1, 1, 1);
    ISSUE_B(Bh1_1, 1, 1);
    WAITV(8);
    BAR(); SCHED0();

    const int NT = K >> 6;              // 16 (K=1024) or 32 (K=2048); even
    for (int u = 0; u < NT; u += 2) {
        TILE256(Ah0_0, Ah1_0, Bh0_0, Bh1_0, u);
        TILE256(Ah0_1, Ah1_1, Bh0_1, Bh1_1, u + 1);
    }

    // drain remaining dummy DMA before epilogue
    asm volatile("s_waitcnt vmcnt(0)" ::: "memory");

#undef ISSUE_A
#undef ISSUE_B
#undef WAITV
#undef READ_A
#undef READ_B
#undef MFMA8
#undef BAR
#undef SCHED0
#undef TILE256

    // ---- epilogue. 16x16 C/D layout: col = l&15, row = (l>>4)*4 + reg
#pragma unroll
    for (int mi = 0; mi < 8; ++mi) {
        const long grow = bm + wm * 128 + mi * 16 + fg * 4;
#pragma unroll
        for (int ni = 0; ni < 4; ++ni) {
            const long gcol = bn + wn * 64 + ni * 16 + fr;
            const f32x4 a = acc[mi][ni];
            if constexpr (EPI == 0) {
                if (gcol < 1024) {
                    const float bias = bq[gcol];
#pragma unroll
                    for (int r = 0; r < 4; ++r)
                        Qb[(grow + r) * 1024 + gcol] = f2b((a[r] + bias) * 0.03125f);
                } else if (gcol < 2048) {
                    const float bias = bk[gcol - 1024];
#pragma unroll
                    for (int r = 0; r < 4; ++r)
                        Kb[(grow + r) * 1024 + (gcol - 1024)] = f2b(a[r] + bias);
                } else {
                    const float bias = bv[gcol - 2048];
                    const long batch = grow >> 11;
                    const int n = (int)(grow & 2047);   // multiple of 4
                    ushort4 o;
                    o.x = f2b(a[0] + bias);
                    o.y = f2b(a[1] + bias);
                    o.z = f2b(a[2] + bias);
                    o.w = f2b(a[3] + bias);
                    *(ushort4*)&Vt[(batch * 1024 + (gcol - 2048)) * 2048 + n] = o;
                }
            } else {
                unsigned short* S = (unsigned short*)Cv + (long)blockIdx.z * sC;
#pragma unroll
                for (int r = 0; r < 4; ++r)
                    S[(grow + r) * 2048 + gcol] = f2b(a[r]);
            }
        }
    }
}

// ---------------- row softmax over 2048 bf16, in place ----------------
__global__ __launch_bounds__(256) void softmax_kernel(unsigned short* __restrict__ S) {
    const long row = blockIdx.x;
    unsigned short* p = S + row * 2048;
    const int tid = threadIdx.x;
    const int wave = tid >> 6, lane = tid & 63;

    ushort4 u0 = *(const ushort4*)&p[tid * 8];
    ushort4 u1 = *(const ushort4*)&p[tid * 8 + 4];
    float v[8];
    v[0] = b2f(u0.x); v[1] = b2f(u0.y); v[2] = b2f(u0.z); v[3] = b2f(u0.w);
    v[4] = b2f(u1.x); v[5] = b2f(u1.y); v[6] = b2f(u1.z); v[7] = b2f(u1.w);

    float m = v[0];
#pragma unroll
    for (int j = 1; j < 8; ++j) m = fmaxf(m, v[j]);
#pragma unroll
    for (int off = 32; off; off >>= 1) m = fmaxf(m, __shfl_xor(m, off, 64));
    __shared__ float redm[4];
    __shared__ float reds[4];
    if (lane == 0) redm[wave] = m;
    __syncthreads();
    m = fmaxf(fmaxf(redm[0], redm[1]), fmaxf(redm[2], redm[3]));

    float s = 0.0f;
#pragma unroll
    for (int j = 0; j < 8; ++j) { v[j] = __expf(v[j] - m); s += v[j]; }
#pragma unroll
    for (int off = 32; off; off >>= 1) s += __shfl_xor(s, off, 64);
    if (lane == 0) reds[wave] = s;
    __syncthreads();
    s = reds[0] + reds[1] + reds[2] + reds[3];
    const float inv = 1.0f / s;

    u0.x = f2b(v[0] * inv); u0.y = f2b(v[1] * inv); u0.z = f2b(v[2] * inv); u0.w = f2b(v[3] * inv);
    u1.x = f2b(v[4] * inv); u1.y = f2b(v[5] * inv); u1.z = f2b(v[6] * inv); u1.w = f2b(v[7] * inv);
    *(ushort4*)&p[tid * 8] = u0;
    *(ushort4*)&p[tid * 8 + 4] = u1;
}

extern "C" void kernel_launch(void* const* d_in, const int* in_sizes, int n_in,
                              void* d_out, int out_size, void* d_ws, size_t ws_size,
                              hipStream_t stream) {
    const float* x  = (const float*)d_in[0];
    const float* Wq = (const float*)d_in[1];
    const float* Wk = (const float*)d_in[2];
    const float* Wv = (const float*)d_in[3];
    const float* bq = (const float*)d_in[4];
    const float* bk = (const float*)d_in[5];
    const float* bv = (const float*)d_in[6];
    float* out = (float*)d_out;

    char* ws = (char*)d_ws;
    unsigned short* xb = (unsigned short*)ws; ws += 8192L * 1024 * 2;
    unsigned short* Wt = (unsigned short*)ws; ws += 3072L * 1024 * 2;
    unsigned short* Qb = (unsigned short*)ws; ws += 8192L * 1024 * 2;
    unsigned short* Kb = (unsigned short*)ws; ws += 8192L * 1024 * 2;
    unsigned short* Vt = (unsigned short*)ws; ws += 4L * 1024 * 2048 * 2;
    unsigned short* S  = (unsigned short*)ws; ws += 4L * 2048 * 2048 * 2;

    // 1. x -> bf16
    convert_x_kernel<<<8192, 256, 0, stream>>>(x, xb);
    // 2. W -> Wt (bf16, transposed, packed [3072][1024])
    transpose_w_kernel<<<dim3(32, 32, 3), dim3(32, 32), 0, stream>>>(Wq, Wk, Wv, Wt);
    // 3. QKV projection: [8192,3072] = xb @ Wt^T (+bias, Q scaled, V stored transposed)
    gemm256<0><<<dim3(12, 32, 1), 512, 0, stream>>>(xb, 1024, 0, Wt, 1024, 0,
                                                    nullptr, 0, 1024, bq, bk, bv, Qb, Kb, Vt);
    // 4. per-batch scores: S[b] = Q[b] @ K[b]^T  (Q pre-scaled by 1/32)
    gemm256<1><<<dim3(8, 8, 4), 512, 0, stream>>>(Qb, 1024, 2048L * 1024, Kb, 1024, 2048L * 1024,
                                                  S, 2048L * 2048, 1024,
                                                  nullptr, nullptr, nullptr, nullptr, nullptr, nullptr);
    // 5. softmax rows (in place, bf16)
    softmax_kernel<<<8192, 256, 0, stream>>>(S);
    // 6. out[b] = P[b] @ Vt[b]^T  (fp32 out)
    gemm32<2><<<dim3(8, 16, 4), 256, 0, stream>>>(S, 2048, 2048L * 2048, Vt, 2048, 2048L * 1024,
                                                  out, 2048L * 1024, 2048,
                                                  nullptr, nullptr, nullptr, nullptr, nullptr, nullptr);
}

// Round 7
// 259.061 us; speedup vs baseline: 1.1455x; 1.0635x over previous
//
#include <hip/hip_runtime.h>
#include <cstdint>

typedef __bf16 bf16x8 __attribute__((ext_vector_type(8)));
typedef float f32x16 __attribute__((ext_vector_type(16)));

__device__ __forceinline__ unsigned short f2b(float f) {
    union { float f; uint32_t u; } x; x.f = f;
    uint32_t r = (x.u + 0x7fffu + ((x.u >> 16) & 1u)) >> 16;
    return (unsigned short)r;
}
__device__ __forceinline__ float b2f(unsigned short h) {
    union { float f; uint32_t u; } x; x.u = ((uint32_t)h) << 16;
    return x.f;
}

// ------- fused prep: x fp32->bf16 (blocks 0..8191) + W transpose->bf16 (blocks 8192..11263) -------
__global__ __launch_bounds__(256) void prep_kernel(const float* __restrict__ x,
                                                   unsigned short* __restrict__ xb,
                                                   const float* __restrict__ Wq,
                                                   const float* __restrict__ Wk,
                                                   const float* __restrict__ Wv,
                                                   unsigned short* __restrict__ Wt) {
    const int bid = blockIdx.x;
    const int tid = threadIdx.x;
    if (bid < 8192) {
        int i = (bid * 256 + tid) * 4;
        float4 v = *(const float4*)(x + i);
        ushort4 o;
        o.x = f2b(v.x); o.y = f2b(v.y); o.z = f2b(v.z); o.w = f2b(v.w);
        *(ushort4*)(xb + i) = o;
    } else {
        __shared__ float tile[32][33];
        const int b = bid - 8192;          // 0..3071
        const int z = b >> 10;             // which W
        const int rem = b & 1023;
        const int n0 = (rem & 31) * 32;
        const int k0 = (rem >> 5) * 32;
        const float* W = (z == 0) ? Wq : (z == 1) ? Wk : Wv;
        const int tx = tid & 31, ty4 = tid >> 5;   // 0..7
#pragma unroll
        for (int i = 0; i < 4; ++i)
            tile[ty4 * 4 + i][tx] = W[(k0 + ty4 * 4 + i) * 1024 + n0 + tx];
        __syncthreads();
#pragma unroll
        for (int i = 0; i < 4; ++i) {
            const int row = ty4 * 4 + i;   // n within tile
            Wt[((long)z * 1024 + n0 + row) * 1024 + k0 + tx] = f2b(tile[tx][row]);
        }
    }
}

// ---------------- BT-form bf16 MFMA GEMM: C[m][n] = sum_k A[m][k]*B[n][k] ----------------
// 128x128 block tile, BK=64, 256 threads (4 waves, 2x2 of 32x32 wave-tiles via
// v_mfma_f32_32x32x16_bf16). LDS rows hold 64 bf16 (128 B = all 32 banks) with an
// XOR-swizzle on 16B chunks: phys_chunk = log_chunk ^ (row & 7), applied at staging time
// by permuting which global chunk each lane fetches (global_load_lds dest stays lane-linear).
//
// K-loop is DOUBLE-BUFFERED with ONE barrier per K-step (T3 "minimum 2-phase"):
// the next tile's global_load_lds are issued BEFORE the current tile's compute, so the
// barrier's compiler-emitted vmcnt(0) drain waits on loads that have had a full compute
// phase (~300+ cyc of MFMA/ds_read) in flight. Two K-steps are unrolled per loop
// iteration so the two buffers are statically distinct arrays. K must be a multiple of 128.
//
// Verified best structure for this problem (r2: QKV 69.6us @740TF; 256^2 8-phase port
// measured SLOWER across r4-r6 — 86-102us — due to unreproduced fine interleave at 1 blk/CU).
//
// EPI 0: QKV projection epilogue (bias, Q scale 1/32, V transposed store)
// EPI 1: bf16 store to S (ldc=2048)
// EPI 2: fp32 store to out (ldc=1024)
template <int EPI>
__global__ __launch_bounds__(256) void gemm32(const unsigned short* __restrict__ A, int lda, long sA,
                                              const unsigned short* __restrict__ Bm, int ldb, long sB,
                                              void* __restrict__ Cv, long sC, int K,
                                              const float* __restrict__ bq, const float* __restrict__ bk,
                                              const float* __restrict__ bv,
                                              unsigned short* __restrict__ Qb,
                                              unsigned short* __restrict__ Kb,
                                              unsigned short* __restrict__ Vt) {
    __shared__ unsigned short As0[128 * 64];
    __shared__ unsigned short Bs0[128 * 64];
    __shared__ unsigned short As1[128 * 64];
    __shared__ unsigned short Bs1[128 * 64];

    const int tid = threadIdx.x;
    const int wave = tid >> 6, lane = tid & 63;
    const int h = lane >> 5;
    const int l31 = lane & 31;
    const int wm = wave >> 1, wn = wave & 1;
    const long bm = (long)blockIdx.y * 128;
    const long bn = (long)blockIdx.x * 128;

    const unsigned short* Ab = A + (long)blockIdx.z * sA;
    const unsigned short* Bb = Bm + (long)blockIdx.z * sB;

    f32x16 acc[2][2];
#pragma unroll
    for (int mi = 0; mi < 2; ++mi) {
#pragma unroll
        for (int ni = 0; ni < 2; ++ni) {
#pragma unroll
            for (int r = 0; r < 16; ++r) acc[mi][ni][r] = 0.0f;
        }
    }

    const int srow_in = lane >> 3;
    const int cswz = (lane & 7) ^ srow_in;
    const unsigned short* aptr[4];
    const unsigned short* bptr[4];
    int sloff[4];
#pragma unroll
    for (int j = 0; j < 4; ++j) {
        const int row = j * 32 + wave * 8 + srow_in;
        aptr[j] = Ab + (bm + row) * (long)lda + cswz * 8;
        bptr[j] = Bb + (bn + row) * (long)ldb + cswz * 8;
        sloff[j] = (j * 32 + wave * 8) * 64;
    }

    const int arow0 = (wm * 64 + l31) * 64;
    const int brow0 = (wn * 64 + l31) * 64;
    int sw[4];
#pragma unroll
    for (int kh = 0; kh < 4; ++kh)
        sw[kh] = (((2 * kh + h) ^ (lane & 7)) * 8);

#define STAGE(AsB, BsB, kofs)                                                                           \
    do {                                                                                                \
        _Pragma("unroll")                                                                               \
        for (int j = 0; j < 4; ++j) {                                                                   \
            __builtin_amdgcn_global_load_lds(                                                           \
                (const __attribute__((address_space(1))) void*)(aptr[j] + (kofs)),                      \
                (__attribute__((address_space(3))) void*)(&AsB[sloff[j]]), 16, 0, 0);                   \
            __builtin_amdgcn_global_load_lds(                                                           \
                (const __attribute__((address_space(1))) void*)(bptr[j] + (kofs)),                      \
                (__attribute__((address_space(3))) void*)(&BsB[sloff[j]]), 16, 0, 0);                   \
        }                                                                                               \
    } while (0)

#define COMPUTE_T(AsB, BsB)                                                                             \
    do {                                                                                                \
        _Pragma("unroll")                                                                               \
        for (int kp = 0; kp < 2; ++kp) {                                                                \
            bf16x8 af[2][2], bfr[2][2];                                                                 \
            _Pragma("unroll")                                                                           \
            for (int mi = 0; mi < 2; ++mi) {                                                            \
                _Pragma("unroll")                                                                       \
                for (int kk = 0; kk < 2; ++kk) {                                                        \
                    af[mi][kk] = *(const bf16x8*)&AsB[arow0 + mi * 32 * 64 + sw[kp * 2 + kk]];          \
                }                                                                                       \
            }                                                                                           \
            _Pragma("unroll")                                                                           \
            for (int ni = 0; ni < 2; ++ni) {                                                            \
                _Pragma("unroll")                                                                       \
                for (int kk = 0; kk < 2; ++kk) {                                                        \
                    bfr[ni][kk] = *(const bf16x8*)&BsB[brow0 + ni * 32 * 64 + sw[kp * 2 + kk]];         \
                }                                                                                       \
            }                                                                                           \
            _Pragma("unroll")                                                                           \
            for (int kk = 0; kk < 2; ++kk) {                                                            \
                _Pragma("unroll")                                                                       \
                for (int mi = 0; mi < 2; ++mi) {                                                        \
                    _Pragma("unroll")                                                                   \
                    for (int ni = 0; ni < 2; ++ni) {                                                    \
                        acc[mi][ni] = __builtin_amdgcn_mfma_f32_32x32x16_bf16(af[mi][kk], bfr[ni][kk],  \
                                                                              acc[mi][ni], 0, 0, 0);    \
                    }                                                                                   \
                }                                                                                       \
            }                                                                                           \
        }                                                                                               \
    } while (0)

    STAGE(As0, Bs0, 0);

    for (int k0 = 0; k0 < K; k0 += 128) {
        __syncthreads();
        STAGE(As1, Bs1, k0 + 64);
        COMPUTE_T(As0, Bs0);
        __syncthreads();
        if (k0 + 128 < K) STAGE(As0, Bs0, k0 + 128);
        COMPUTE_T(As1, Bs1);
    }

#undef STAGE
#undef COMPUTE_T

#pragma unroll
    for (int mi = 0; mi < 2; ++mi) {
#pragma unroll
        for (int ni = 0; ni < 2; ++ni) {
            const f32x16 a = acc[mi][ni];
            const long col = bn + wn * 64 + ni * 32 + l31;
            const long rowB = bm + wm * 64 + mi * 32 + h * 4;
            if constexpr (EPI == 0) {
                if (col < 1024) {
                    const float bias = bq[col];
#pragma unroll
                    for (int g = 0; g < 4; ++g) {
#pragma unroll
                        for (int r = 0; r < 4; ++r)
                            Qb[(rowB + g * 8 + r) * 1024 + col] = f2b((a[g * 4 + r] + bias) * 0.03125f);
                    }
                } else if (col < 2048) {
                    const float bias = bk[col - 1024];
#pragma unroll
                    for (int g = 0; g < 4; ++g) {
#pragma unroll
                        for (int r = 0; r < 4; ++r)
                            Kb[(rowB + g * 8 + r) * 1024 + (col - 1024)] = f2b(a[g * 4 + r] + bias);
                    }
                } else {
                    const float bias = bv[col - 2048];
#pragma unroll
                    for (int g = 0; g < 4; ++g) {
                        const long row0 = rowB + g * 8;
                        const long batch = row0 >> 11;
                        const int n = (int)(row0 & 2047);
                        ushort4 o;
                        o.x = f2b(a[g * 4 + 0] + bias);
                        o.y = f2b(a[g * 4 + 1] + bias);
                        o.z = f2b(a[g * 4 + 2] + bias);
                        o.w = f2b(a[g * 4 + 3] + bias);
                        *(ushort4*)&Vt[(batch * 1024 + (col - 2048)) * 2048 + n] = o;
                    }
                }
            } else if constexpr (EPI == 1) {
                unsigned short* S = (unsigned short*)Cv + (long)blockIdx.z * sC;
#pragma unroll
                for (int g = 0; g < 4; ++g) {
#pragma unroll
                    for (int r = 0; r < 4; ++r)
                        S[(rowB + g * 8 + r) * 2048 + col] = f2b(a[g * 4 + r]);
                }
            } else {
                float* O = (float*)Cv + (long)blockIdx.z * sC;
#pragma unroll
                for (int g = 0; g < 4; ++g) {
#pragma unroll
                    for (int r = 0; r < 4; ++r)
                        O[(rowB + g * 8 + r) * 1024 + col] = a[g * 4 + r];
                }
            }
        }
    }
}

// ---------------- row softmax over 2048 bf16, in place ----------------
__global__ __launch_bounds__(256) void softmax_kernel(unsigned short* __restrict__ S) {
    const long row = blockIdx.x;
    unsigned short* p = S + row * 2048;
    const int tid = threadIdx.x;
    const int wave = tid >> 6, lane = tid & 63;

    ushort4 u0 = *(const ushort4*)&p[tid * 8];
    ushort4 u1 = *(const ushort4*)&p[tid * 8 + 4];
    float v[8];
    v[0] = b2f(u0.x); v[1] = b2f(u0.y); v[2] = b2f(u0.z); v[3] = b2f(u0.w);
    v[4] = b2f(u1.x); v[5] = b2f(u1.y); v[6] = b2f(u1.z); v[7] = b2f(u1.w);

    float m = v[0];
#pragma unroll
    for (int j = 1; j < 8; ++j) m = fmaxf(m, v[j]);
#pragma unroll
    for (int off = 32; off; off >>= 1) m = fmaxf(m, __shfl_xor(m, off, 64));
    __shared__ float redm[4];
    __shared__ float reds[4];
    if (lane == 0) redm[wave] = m;
    __syncthreads();
    m = fmaxf(fmaxf(redm[0], redm[1]), fmaxf(redm[2], redm[3]));

    float s = 0.0f;
#pragma unroll
    for (int j = 0; j < 8; ++j) { v[j] = __expf(v[j] - m); s += v[j]; }
#pragma unroll
    for (int off = 32; off; off >>= 1) s += __shfl_xor(s, off, 64);
    if (lane == 0) reds[wave] = s;
    __syncthreads();
    s = reds[0] + reds[1] + reds[2] + reds[3];
    const float inv = 1.0f / s;

    u0.x = f2b(v[0] * inv); u0.y = f2b(v[1] * inv); u0.z = f2b(v[2] * inv); u0.w = f2b(v[3] * inv);
    u1.x = f2b(v[4] * inv); u1.y = f2b(v[5] * inv); u1.z = f2b(v[6] * inv); u1.w = f2b(v[7] * inv);
    *(ushort4*)&p[tid * 8] = u0;
    *(ushort4*)&p[tid * 8 + 4] = u1;
}

extern "C" void kernel_launch(void* const* d_in, const int* in_sizes, int n_in,
                              void* d_out, int out_size, void* d_ws, size_t ws_size,
                              hipStream_t stream) {
    const float* x  = (const float*)d_in[0];
    const float* Wq = (const float*)d_in[1];
    const float* Wk = (const float*)d_in[2];
    const float* Wv = (const float*)d_in[3];
    const float* bq = (const float*)d_in[4];
    const float* bk = (const float*)d_in[5];
    const float* bv = (const float*)d_in[6];
    float* out = (float*)d_out;

    char* ws = (char*)d_ws;
    unsigned short* xb = (unsigned short*)ws; ws += 8192L * 1024 * 2;
    unsigned short* Wt = (unsigned short*)ws; ws += 3072L * 1024 * 2;
    unsigned short* Qb = (unsigned short*)ws; ws += 8192L * 1024 * 2;
    unsigned short* Kb = (unsigned short*)ws; ws += 8192L * 1024 * 2;
    unsigned short* Vt = (unsigned short*)ws; ws += 4L * 1024 * 2048 * 2;
    unsigned short* S  = (unsigned short*)ws; ws += 4L * 2048 * 2048 * 2;

    // 1. fused: x -> bf16  +  W -> Wt (bf16, transposed, packed [3072][1024])
    prep_kernel<<<8192 + 3072, 256, 0, stream>>>(x, xb, Wq, Wk, Wv, Wt);
    // 2. QKV projection: [8192,3072] = xb @ Wt^T (+bias, Q scaled, V stored transposed)
    gemm32<0><<<dim3(24, 64, 1), 256, 0, stream>>>(xb, 1024, 0, Wt, 1024, 0,
                                                   nullptr, 0, 1024, bq, bk, bv, Qb, Kb, Vt);
    // 3. per-batch scores: S[b] = Q[b] @ K[b]^T  (Q pre-scaled by 1/32)
    gemm32<1><<<dim3(16, 16, 4), 256, 0, stream>>>(Qb, 1024, 2048L * 1024, Kb, 1024, 2048L * 1024,
                                                   S, 2048L * 2048, 1024,
                                                   nullptr, nullptr, nullptr, nullptr, nullptr, nullptr);
    // 4. softmax rows (in place, bf16)
    softmax_kernel<<<8192, 256, 0, stream>>>(S);
    // 5. out[b] = P[b] @ Vt[b]^T  (fp32 out)
    gemm32<2><<<dim3(8, 16, 4), 256, 0, stream>>>(S, 2048, 2048L * 2048, Vt, 2048, 2048L * 1024,
                                                  out, 2048L * 1024, 2048,
                                                  nullptr, nullptr, nullptr, nullptr, nullptr, nullptr);
}